// Round 1
// baseline (5737.912 us; speedup 1.0000x reference)
//
#include <hip/hip_runtime.h>
#include <hip/hip_bf16.h>

// ESN: h_m = tanh(W_res h_{m-1} + W_in x_{m-1} + b_in), readout on all states.
// Strategy: split-bf16 (hi/lo) MFMA for u-GEMM and recurrence (fp32-equivalent
// precision), plain-bf16 MFMA for readout. States stored as bf16 hi/lo pairs;
// u written in place into states[m] and overwritten by h_m.

#define B_   64
#define T_   256
#define DIN  512
#define DRES 2048
#define DOUT 512

typedef __attribute__((ext_vector_type(8))) short short8;
typedef __attribute__((ext_vector_type(4))) float f32x4;

__device__ __forceinline__ unsigned short f2bf(float x) {
    unsigned int u = __float_as_uint(x);
    unsigned int r = u + 0x7fffu + ((u >> 16) & 1u);
    return (unsigned short)(r >> 16);
}
__device__ __forceinline__ float bf2f(unsigned short h) {
    return __uint_as_float(((unsigned int)h) << 16);
}

// ---------------- split f32 -> bf16 hi/lo ----------------
__global__ void split4_kern(const float4* __restrict__ src,
                            ushort4* __restrict__ hi, ushort4* __restrict__ lo, int n4) {
    int i = blockIdx.x * blockDim.x + threadIdx.x;
    int st = gridDim.x * blockDim.x;
    for (; i < n4; i += st) {
        float4 v = src[i];
        ushort4 h, l;
        h.x = f2bf(v.x); l.x = f2bf(v.x - bf2f(h.x));
        h.y = f2bf(v.y); l.y = f2bf(v.y - bf2f(h.y));
        h.z = f2bf(v.z); l.z = f2bf(v.z - bf2f(h.z));
        h.w = f2bf(v.w); l.w = f2bf(v.w - bf2f(h.w));
        hi[i] = h; lo[i] = l;
    }
}

// ---------------- u GEMM: states[m] = x_in[:,m-1,:] @ W_in^T + b_in ----------------
// grid (32 r-tiles, 255 t), block 256 (4 waves). WG tile [64b x 64r], K=512.
__global__ __launch_bounds__(256) void u_gemm(
    const unsigned short* __restrict__ x_hi, const unsigned short* __restrict__ x_lo,
    const unsigned short* __restrict__ Win_hi, const unsigned short* __restrict__ Win_lo,
    const float* __restrict__ b_in,
    unsigned short* __restrict__ st_hi, unsigned short* __restrict__ st_lo) {
    const int t = blockIdx.y;            // 0..254 -> m = t+1
    const int r0 = blockIdx.x * 64;
    const int tid = threadIdx.x;
    const int w = tid >> 6, l = tid & 63;
    const int lm = l & 15, lg = l >> 4;

    __shared__ __align__(16) unsigned short Bs[2][64][72];  // [hi/lo][r][k] pad->72

    f32x4 acc[4][3];
#pragma unroll
    for (int nt = 0; nt < 4; ++nt)
#pragma unroll
        for (int q = 0; q < 3; ++q) acc[nt][q] = (f32x4)0.0f;

    const int ab = w * 16 + lm;                       // A row (b)
    const long xbase = ((long)ab * T_ + t) * DIN;

    for (int s = 0; s < 8; ++s) {                     // K stages of 64
#pragma unroll
        for (int q = 0; q < 4; ++q) {                 // stage B: 2*64*64 = 1024 short8
            int idx = q * 256 + tid;
            int mt = idx >> 9;
            int rem = idx & 511;
            int row = rem >> 3, k8 = rem & 7;
            const unsigned short* sp =
                (mt ? Win_lo : Win_hi) + (long)(r0 + row) * DIN + s * 64 + k8 * 8;
            *(short8*)&Bs[mt][row][k8 * 8] = *(const short8*)sp;
        }
        __syncthreads();
#pragma unroll
        for (int ki = 0; ki < 2; ++ki) {
            int k = s * 64 + ki * 32 + lg * 8;
            short8 ahi = *(const short8*)&x_hi[xbase + k];
            short8 alo = *(const short8*)&x_lo[xbase + k];
#pragma unroll
            for (int nt = 0; nt < 4; ++nt) {
                short8 bhi = *(const short8*)&Bs[0][nt * 16 + lm][ki * 32 + lg * 8];
                short8 blo = *(const short8*)&Bs[1][nt * 16 + lm][ki * 32 + lg * 8];
                acc[nt][0] = __builtin_amdgcn_mfma_f32_16x16x32_bf16(ahi, bhi, acc[nt][0], 0, 0, 0);
                acc[nt][1] = __builtin_amdgcn_mfma_f32_16x16x32_bf16(ahi, blo, acc[nt][1], 0, 0, 0);
                acc[nt][2] = __builtin_amdgcn_mfma_f32_16x16x32_bf16(alo, bhi, acc[nt][2], 0, 0, 0);
            }
        }
        __syncthreads();
    }
    const int m = t + 1;
#pragma unroll
    for (int nt = 0; nt < 4; ++nt) {
        f32x4 s4 = acc[nt][0] + acc[nt][1] + acc[nt][2];
        int r = r0 + nt * 16 + lm;
        float bias = b_in[r];
#pragma unroll
        for (int j = 0; j < 4; ++j) {
            int bb = w * 16 + lg * 4 + j;
            float v = s4[j] + bias;
            unsigned short h = f2bf(v);
            long o = ((long)m * B_ + bb) * DRES + r;
            st_hi[o] = h;
            st_lo[o] = f2bf(v - bf2f(h));
        }
    }
}

// ---------------- recurrence step: h_m = tanh(h_{m-1} @ W_res^T + u_m) ----------------
// grid 128 (r-tiles of 16), block 512 (8 waves = 4 b-tiles x 2 K-halves).
__global__ __launch_bounds__(512) void step_kern(
    const unsigned short* __restrict__ hp_hi, const unsigned short* __restrict__ hp_lo,
    unsigned short* __restrict__ hc_hi, unsigned short* __restrict__ hc_lo,
    const unsigned short* __restrict__ W_hi, const unsigned short* __restrict__ W_lo) {
    const int r0 = blockIdx.x * 16;
    const int tid = threadIdx.x;
    const int w = tid >> 6, l = tid & 63;
    const int lm = l & 15, lg = l >> 4;
    const int bt = w & 3, kh = w >> 2;
    const int b0 = bt * 16;

    __shared__ __align__(16) unsigned short Bs[2][2][16][264];  // [kh][hi/lo][r][k] pad->264
    __shared__ float red[64][17];

    f32x4 a0 = (f32x4)0.f, a1 = (f32x4)0.f, a2 = (f32x4)0.f;
    const long abase = (long)(b0 + lm) * DRES;

    for (int s = 0; s < 4; ++s) {                     // stages of 256 per K-half
#pragma unroll
        for (int q = 0; q < 4; ++q) {                 // stage B: 2*2*16*256 = 2048 short8
            int idx = q * 512 + tid;
            int khs = idx >> 10;
            int mt = (idx >> 9) & 1;
            int row = (idx >> 5) & 15;
            int k8 = idx & 31;
            const unsigned short* sp =
                (mt ? W_lo : W_hi) + (long)(r0 + row) * DRES + khs * 1024 + s * 256 + k8 * 8;
            *(short8*)&Bs[khs][mt][row][k8 * 8] = *(const short8*)sp;
        }
        __syncthreads();
#pragma unroll
        for (int ki = 0; ki < 8; ++ki) {
            int k = kh * 1024 + s * 256 + ki * 32 + lg * 8;
            short8 ahi = *(const short8*)&hp_hi[abase + k];
            short8 alo = *(const short8*)&hp_lo[abase + k];
            short8 bhi = *(const short8*)&Bs[kh][0][lm][ki * 32 + lg * 8];
            short8 blo = *(const short8*)&Bs[kh][1][lm][ki * 32 + lg * 8];
            a0 = __builtin_amdgcn_mfma_f32_16x16x32_bf16(ahi, bhi, a0, 0, 0, 0);
            a1 = __builtin_amdgcn_mfma_f32_16x16x32_bf16(ahi, blo, a1, 0, 0, 0);
            a2 = __builtin_amdgcn_mfma_f32_16x16x32_bf16(alo, bhi, a2, 0, 0, 0);
        }
        __syncthreads();
    }
    f32x4 sum = a0 + a1 + a2;
    if (kh == 1) {
#pragma unroll
        for (int j = 0; j < 4; ++j) red[b0 + lg * 4 + j][lm] = sum[j];
    }
    __syncthreads();
    if (kh == 0) {
        int r = r0 + lm;
#pragma unroll
        for (int j = 0; j < 4; ++j) {
            int bb = b0 + lg * 4 + j;
            long o = (long)bb * DRES + r;
            float u = bf2f(hc_hi[o]) + bf2f(hc_lo[o]);   // u_m was stored here
            float pre = sum[j] + red[bb][lm] + u;
            float h = tanhf(pre);
            unsigned short hh = f2bf(h);
            hc_hi[o] = hh;
            hc_lo[o] = f2bf(h - bf2f(hh));
        }
    }
}

// ---------------- readout: out[b][t][o] = states[t][b][:] . W_out[o][:] + b_out ----------------
// grid (4 n-tiles of 128, 256 row-tiles of 64), block 256 (4 waves). Plain bf16.
__global__ __launch_bounds__(256) void readout_kern(
    const unsigned short* __restrict__ st_hi,
    const unsigned short* __restrict__ Wout_hi,
    const float* __restrict__ b_out, float* __restrict__ out) {
    const int n0 = blockIdx.x * 128;
    const int row0 = blockIdx.y * 64;
    const int tid = threadIdx.x;
    const int w = tid >> 6, l = tid & 63;
    const int lm = l & 15, lg = l >> 4;

    __shared__ __align__(16) unsigned short Bs[128][72];

    f32x4 acc[8];
#pragma unroll
    for (int nt = 0; nt < 8; ++nt) acc[nt] = (f32x4)0.f;

    const int row = row0 + w * 16 + lm;
    const long abase = (long)row * DRES;

    for (int s = 0; s < 32; ++s) {                    // K stages of 64
#pragma unroll
        for (int q = 0; q < 4; ++q) {                 // stage B: 128*64 = 1024 short8
            int idx = q * 256 + tid;
            int r_ = idx >> 3, k8 = idx & 7;
            *(short8*)&Bs[r_][k8 * 8] =
                *(const short8*)(Wout_hi + (long)(n0 + r_) * DRES + s * 64 + k8 * 8);
        }
        __syncthreads();
#pragma unroll
        for (int ki = 0; ki < 2; ++ki) {
            short8 a = *(const short8*)&st_hi[abase + s * 64 + ki * 32 + lg * 8];
#pragma unroll
            for (int nt = 0; nt < 8; ++nt) {
                short8 bf = *(const short8*)&Bs[nt * 16 + lm][ki * 32 + lg * 8];
                acc[nt] = __builtin_amdgcn_mfma_f32_16x16x32_bf16(a, bf, acc[nt], 0, 0, 0);
            }
        }
        __syncthreads();
    }
#pragma unroll
    for (int nt = 0; nt < 8; ++nt) {
        int o = n0 + nt * 16 + lm;
        float bias = b_out[o];
#pragma unroll
        for (int j = 0; j < 4; ++j) {
            int rr = row0 + w * 16 + lg * 4 + j;
            int t = rr >> 6, bb = rr & 63;
            out[((long)bb * T_ + t) * DOUT + o] = acc[nt][j] + bias;
        }
    }
}

extern "C" void kernel_launch(void* const* d_in, const int* in_sizes, int n_in,
                              void* d_out, int out_size, void* d_ws, size_t ws_size,
                              hipStream_t stream) {
    const float* x_res_init = (const float*)d_in[0];
    const float* x_in       = (const float*)d_in[1];
    const float* W_in       = (const float*)d_in[2];
    const float* b_in       = (const float*)d_in[3];
    const float* W_res      = (const float*)d_in[4];
    const float* W_out      = (const float*)d_in[5];
    const float* b_out      = (const float*)d_in[6];
    float* out = (float*)d_out;

    char* p = (char*)d_ws;
    auto alloc = [&](size_t bytes) -> char* {
        char* r = p;
        p += (bytes + 255) & ~(size_t)255;
        return r;
    };
    const size_t SL = (size_t)B_ * DRES;  // one state slice (elements)
    unsigned short* st_hi   = (unsigned short*)alloc((size_t)T_ * SL * 2);
    unsigned short* st_lo   = (unsigned short*)alloc((size_t)T_ * SL * 2);
    unsigned short* Wres_hi = (unsigned short*)alloc((size_t)DRES * DRES * 2);
    unsigned short* Wres_lo = (unsigned short*)alloc((size_t)DRES * DRES * 2);
    unsigned short* Win_hi  = (unsigned short*)alloc((size_t)DRES * DIN * 2);
    unsigned short* Win_lo  = (unsigned short*)alloc((size_t)DRES * DIN * 2);
    unsigned short* Wout_hi = (unsigned short*)alloc((size_t)DOUT * DRES * 2);
    unsigned short* Wout_lo = (unsigned short*)alloc((size_t)DOUT * DRES * 2);
    unsigned short* x_hi    = (unsigned short*)alloc((size_t)B_ * T_ * DIN * 2);
    unsigned short* x_lo    = (unsigned short*)alloc((size_t)B_ * T_ * DIN * 2);
    // total ~193 MB of d_ws

    auto launch_split = [&](const float* src, unsigned short* hi, unsigned short* lo, size_t n) {
        int n4 = (int)(n / 4);
        int blocks = (n4 + 255) / 256;
        if (blocks > 2048) blocks = 2048;
        split4_kern<<<blocks, 256, 0, stream>>>((const float4*)src, (ushort4*)hi, (ushort4*)lo, n4);
    };
    launch_split(W_res, Wres_hi, Wres_lo, (size_t)DRES * DRES);
    launch_split(W_in,  Win_hi,  Win_lo,  (size_t)DRES * DIN);
    launch_split(W_out, Wout_hi, Wout_lo, (size_t)DOUT * DRES);
    launch_split(x_in,  x_hi,    x_lo,    (size_t)B_ * T_ * DIN);
    launch_split(x_res_init, st_hi, st_lo, SL);  // states[0]

    // u into states[1..255]
    u_gemm<<<dim3(32, T_ - 1), 256, 0, stream>>>(x_hi, x_lo, Win_hi, Win_lo, b_in, st_hi, st_lo);

    // recurrence
    for (int m = 1; m < T_; ++m) {
        step_kern<<<128, 512, 0, stream>>>(st_hi + (size_t)(m - 1) * SL, st_lo + (size_t)(m - 1) * SL,
                                           st_hi + (size_t)m * SL, st_lo + (size_t)m * SL,
                                           Wres_hi, Wres_lo);
    }

    // readout
    readout_kern<<<dim3(4, 256), 256, 0, stream>>>(st_hi, Wout_hi, b_out, out);
}